// Round 2
// baseline (3768.641 us; speedup 1.0000x reference)
//
#include <hip/hip_runtime.h>
#include <cstdint>
#include <cstddef>

#define B_   64
#define T_   2048
#define C_   64
#define H_   256
#define G3_  768    // 3*H
#define HOR_ 96

typedef _Float16 h2 __attribute__((ext_vector_type(2)));
typedef _Float16 h8 __attribute__((ext_vector_type(8)));

// ---------------------------------------------------------------------------
// K1: cur[b,t,h] = sum_c x[b,t,c]*snn_w[h,c] + snn_b[h]     (fp32)
// ---------------------------------------------------------------------------
#define K1_TT 128
__global__ __launch_bounds__(256) void k_cur(const float* __restrict__ x,
                                             const float* __restrict__ w,
                                             const float* __restrict__ bias,
                                             float* __restrict__ cur) {
  __shared__ float xs[K1_TT * C_];  // 32 KB
  const int b = blockIdx.x;
  const int t0 = blockIdx.y * K1_TT;
  const int tid = threadIdx.x;

  const float4* xsrc = (const float4*)(x + ((size_t)b * T_ + t0) * C_);
  float4* xdst = (float4*)xs;
#pragma unroll
  for (int i = 0; i < (K1_TT * C_ / 4) / 256; i++)
    xdst[tid + i * 256] = xsrc[tid + i * 256];

  float wr[C_];
  const float4* wp = (const float4*)(w + (size_t)tid * C_);
#pragma unroll
  for (int q = 0; q < C_ / 4; q++) {
    float4 v = wp[q];
    wr[4 * q + 0] = v.x; wr[4 * q + 1] = v.y;
    wr[4 * q + 2] = v.z; wr[4 * q + 3] = v.w;
  }
  const float bb = bias[tid];
  __syncthreads();

  for (int t = 0; t < K1_TT; t++) {
    const float4* xrow = (const float4*)(xs + t * C_);
    float a0 = 0.f, a1 = 0.f;
#pragma unroll
    for (int q = 0; q < C_ / 4; q += 2) {
      float4 v0 = xrow[q];
      float4 v1 = xrow[q + 1];
      a0 += wr[4 * q + 0] * v0.x + wr[4 * q + 1] * v0.y +
            wr[4 * q + 2] * v0.z + wr[4 * q + 3] * v0.w;
      a1 += wr[4 * q + 4] * v1.x + wr[4 * q + 5] * v1.y +
            wr[4 * q + 6] * v1.z + wr[4 * q + 7] * v1.w;
    }
    cur[((size_t)b * T_ + t0 + t) * H_ + tid] = a0 + a1 + bb;
  }
}

// ---------------------------------------------------------------------------
// K2: LIF scan per (b,h). Spikes stored as u8 (exact).
// ---------------------------------------------------------------------------
__global__ __launch_bounds__(64) void k_lif(const float* __restrict__ cur,
                                            unsigned char* __restrict__ spk) {
  const int b = blockIdx.x >> 2;
  const int h = ((blockIdx.x & 3) << 6) + threadIdx.x;
  const float* cp = cur + (size_t)b * T_ * H_ + h;
  unsigned char* sp = spk + (size_t)b * T_ * H_ + h;
  float mem = 0.f;
#pragma unroll 8
  for (int t = 0; t < T_; t++) {
    float c = cp[(size_t)t * H_];
    float reset = (mem > 1.0f) ? 1.0f : 0.0f;  // from previous mem
    mem = 0.9f * mem + c - reset;              // THR = 1
    sp[(size_t)t * H_] = (mem > 1.0f) ? (unsigned char)1 : (unsigned char)0;
  }
}

// ---------------------------------------------------------------------------
// K3: gx[m,g] = sum_k hcomb[m,k]*wih[g,k] + bih[g]   -> stored fp16
//     hcomb = [x (k<64) | spk (k>=64)], M=131072, K=320, N=768
// fp32 LDS-tiled GEMM: BM=128 BN=64 BK=32, 256 threads, 4x8 per-thread tile.
// ---------------------------------------------------------------------------
#define BM 128
#define BN 64
#define BK 32
__global__ __launch_bounds__(256) void k_gx(const float* __restrict__ x,
                                            const unsigned char* __restrict__ spk,
                                            const float* __restrict__ wih,
                                            const float* __restrict__ bih,
                                            _Float16* __restrict__ gx) {
  __shared__ float As[BK][BM];  // 16 KB
  __shared__ float Bs[BK][BN];  // 8 KB
  const int nb = blockIdx.x;
  const int mb = blockIdx.y;
  const int m0 = mb * BM, n0 = nb * BN;
  const int tid = threadIdx.x;
  const int tm = (tid & 31) * 4;
  const int tn = (tid >> 5) * 8;

  float acc[4][8] = {};

  for (int k0 = 0; k0 < 320; k0 += BK) {
    if (k0 < 64) {
#pragma unroll
      for (int i = 0; i < 4; i++) {
        int idx = tid + i * 256;
        int r = idx >> 3;
        int c4 = (idx & 7) * 4;
        float4 v = *(const float4*)(x + (size_t)(m0 + r) * C_ + k0 + c4);
        As[c4 + 0][r] = v.x; As[c4 + 1][r] = v.y;
        As[c4 + 2][r] = v.z; As[c4 + 3][r] = v.w;
      }
    } else {
#pragma unroll
      for (int i = 0; i < 4; i++) {
        int idx = tid + i * 256;
        int r = idx >> 3;
        int c4 = (idx & 7) * 4;
        uchar4 u = *(const uchar4*)(spk + (size_t)(m0 + r) * H_ + (k0 - 64) + c4);
        As[c4 + 0][r] = (float)u.x; As[c4 + 1][r] = (float)u.y;
        As[c4 + 2][r] = (float)u.z; As[c4 + 3][r] = (float)u.w;
      }
    }
#pragma unroll
    for (int i = 0; i < 2; i++) {
      int idx = tid + i * 256;
      int r = idx >> 3;
      int c4 = (idx & 7) * 4;
      float4 v = *(const float4*)(wih + (size_t)(n0 + r) * 320 + k0 + c4);
      Bs[c4 + 0][r] = v.x; Bs[c4 + 1][r] = v.y;
      Bs[c4 + 2][r] = v.z; Bs[c4 + 3][r] = v.w;
    }
    __syncthreads();
#pragma unroll
    for (int k = 0; k < BK; k++) {
      float a[4], bv[8];
      *(float4*)&a[0] = *(const float4*)&As[k][tm];
      *(float4*)&bv[0] = *(const float4*)&Bs[k][tn];
      *(float4*)&bv[4] = *(const float4*)&Bs[k][tn + 4];
#pragma unroll
      for (int i = 0; i < 4; i++)
#pragma unroll
        for (int jj = 0; jj < 8; jj++) acc[i][jj] += a[i] * bv[jj];
    }
    __syncthreads();
  }
#pragma unroll
  for (int i = 0; i < 4; i++) {
    size_t m = (size_t)(m0 + tm + i);
    h8 o;
#pragma unroll
    for (int jj = 0; jj < 8; jj++)
      o[jj] = (_Float16)(acc[i][jj] + bih[n0 + tn + jj]);
    *(h8*)(gx + m * G3_ + n0 + tn) = o;
  }
}

// ---------------------------------------------------------------------------
// K4: GRU scan, one block per batch. 512 threads = (j in [0,256), kq in [0,2)).
// whh rows {j, 256+j, 512+j} x k-chunk [128*kq, 128*kq+128) as packed half2
// = 192 VGPRs/thread (fits 256-VGPR cap at 2 waves/SIMD). v_dot2_f32_f16.
// h state kept fp32 in LDS; fp16 copy feeds the matvec. Fused head.
// ---------------------------------------------------------------------------
__global__ __launch_bounds__(512) void k_gru(const _Float16* __restrict__ gx,
                                             const float* __restrict__ whh,
                                             const float* __restrict__ bhh,
                                             const float* __restrict__ head_w,
                                             const float* __restrict__ head_b,
                                             float* __restrict__ out) {
  const int b = blockIdx.x;
  const int tid = threadIdx.x;
  const int j = tid & (H_ - 1);
  const int kq = tid >> 8;       // 0 or 1
  const int k0 = kq * 128;

  __shared__ h2    hbuf16[2][H_ / 2];   // 1 KB — fp16 matvec input
  __shared__ float hbuf32[2][H_];       // 2 KB — fp32 state trajectory
  __shared__ float red[3][2][H_];       // 6 KB
  __shared__ float gxs[G3_];            // 3 KB

  // weight slice -> packed half2 registers
  h2 wr[64], wz[64], wn[64];
  {
    const float4* p0 = (const float4*)(whh + (size_t)j * H_ + k0);
    const float4* p1 = (const float4*)(whh + (size_t)(H_ + j) * H_ + k0);
    const float4* p2 = (const float4*)(whh + (size_t)(2 * H_ + j) * H_ + k0);
#pragma unroll
    for (int q = 0; q < 32; q++) {
      float4 a = p0[q];
      wr[2 * q].x = (_Float16)a.x; wr[2 * q].y = (_Float16)a.y;
      wr[2 * q + 1].x = (_Float16)a.z; wr[2 * q + 1].y = (_Float16)a.w;
      float4 c = p1[q];
      wz[2 * q].x = (_Float16)c.x; wz[2 * q].y = (_Float16)c.y;
      wz[2 * q + 1].x = (_Float16)c.z; wz[2 * q + 1].y = (_Float16)c.w;
      float4 d = p2[q];
      wn[2 * q].x = (_Float16)d.x; wn[2 * q].y = (_Float16)d.y;
      wn[2 * q + 1].x = (_Float16)d.z; wn[2 * q + 1].y = (_Float16)d.w;
    }
  }
  const float br_ = bhh[j], bz_ = bhh[H_ + j], bn_ = bhh[2 * H_ + j];
  if (tid < H_) hbuf32[0][tid] = 0.f;
  if (tid < H_ / 2) {
    h2 z0; z0.x = (_Float16)0.f; z0.y = (_Float16)0.f;
    hbuf16[0][tid] = z0;
  }
  __syncthreads();

  const _Float16* gxb = gx + (size_t)b * T_ * G3_;
  int cb = 0;
  for (int t = 0; t < T_; t++) {
    // phase 1: kq==1 waves prefetch gx_t into LDS (overlaps dot phase)
    if (kq == 1) {
      float g0 = (float)gxb[(size_t)t * G3_ + j];
      float g1 = (float)gxb[(size_t)t * G3_ + H_ + j];
      float g2 = (float)gxb[(size_t)t * G3_ + 2 * H_ + j];
      gxs[j] = g0; gxs[H_ + j] = g1; gxs[2 * H_ + j] = g2;
    }
    // phase 2: partial dot products (packed fp16, fp32 accumulate)
    const h2* hv = hbuf16[cb] + kq * 64;
    float ar = 0.f, az = 0.f, an = 0.f;
#pragma unroll
    for (int q = 0; q < 64; q++) {
      h2 hh = hv[q];
      ar = __builtin_amdgcn_fdot2(wr[q], hh, ar, false);
      az = __builtin_amdgcn_fdot2(wz[q], hh, az, false);
      an = __builtin_amdgcn_fdot2(wn[q], hh, an, false);
    }
    red[0][kq][j] = ar; red[1][kq][j] = az; red[2][kq][j] = an;
    __syncthreads();
    // phase 3: reduce + gates + state update
    if (tid < H_) {
      float hr = red[0][0][tid] + red[0][1][tid] + br_;
      float hz = red[1][0][tid] + red[1][1][tid] + bz_;
      float hn = red[2][0][tid] + red[2][1][tid] + bn_;
      float xr = gxs[tid], xz = gxs[H_ + tid], xn = gxs[2 * H_ + tid];
      float r = 1.f / (1.f + __expf(-(xr + hr)));
      float z = 1.f / (1.f + __expf(-(xz + hz)));
      float pre = xn + r * hn;
      float e = __expf(2.f * pre);          // tanh(x) = 1 - 2/(e^{2x}+1)
      float n = 1.f - 2.f / (e + 1.f);
      float hnew = (1.f - z) * n + z * hbuf32[cb][tid];
      hbuf32[cb ^ 1][tid] = hnew;
      ((_Float16*)hbuf16[cb ^ 1])[tid] = (_Float16)hnew;
    }
    cb ^= 1;
    __syncthreads();
  }

  // fused head from fp32 h
  if (tid < HOR_) {
    const float4* hw = (const float4*)(head_w + (size_t)tid * H_);
    const float4* hv4 = (const float4*)hbuf32[cb];
    float acc = head_b[tid];
#pragma unroll
    for (int q = 0; q < H_ / 4; q++) {
      float4 w4 = hw[q];
      float4 v4 = hv4[q];
      acc += w4.x * v4.x + w4.y * v4.y + w4.z * v4.z + w4.w * v4.w;
    }
    out[(size_t)b * HOR_ + tid] = acc;
  }
}

// ---------------------------------------------------------------------------
extern "C" void kernel_launch(void* const* d_in, const int* in_sizes, int n_in,
                              void* d_out, int out_size, void* d_ws, size_t ws_size,
                              hipStream_t stream) {
  const float* x      = (const float*)d_in[0];
  const float* snn_w  = (const float*)d_in[1];
  const float* snn_b  = (const float*)d_in[2];
  const float* wih    = (const float*)d_in[3];
  const float* whh    = (const float*)d_in[4];
  const float* bih    = (const float*)d_in[5];
  const float* bhh    = (const float*)d_in[6];
  const float* head_w = (const float*)d_in[7];
  const float* head_b = (const float*)d_in[8];
  float* out = (float*)d_out;

  // ws layout (235 MB total):
  //   [0, 201326592)          gx fp16 [131072,768]
  //   [0, 134217728)          cur fp32 [131072,256] — alias, dead before k_gx
  //   [201326592, 234881024)  spk u8 [131072,256]
  char* ws = (char*)d_ws;
  _Float16* gx = (_Float16*)ws;
  float* cur = (float*)ws;
  unsigned char* spk = (unsigned char*)(ws + (size_t)201326592);

  k_cur<<<dim3(B_, T_ / K1_TT), 256, 0, stream>>>(x, snn_w, snn_b, cur);
  k_lif<<<dim3(256), 64, 0, stream>>>(cur, spk);
  k_gx<<<dim3(G3_ / BN, (B_ * T_) / BM), 256, 0, stream>>>(x, spk, wih, bih, gx);
  k_gru<<<dim3(B_), 512, 0, stream>>>(gx, whh, bhh, head_w, head_b, out);
}

// Round 3
// 3750.876 us; speedup vs baseline: 1.0047x; 1.0047x over previous
//
#include <hip/hip_runtime.h>
#include <cstdint>
#include <cstddef>

#define B_   64
#define T_   2048
#define C_   64
#define H_   256
#define G3_  768    // 3*H
#define HOR_ 96

typedef _Float16 h2 __attribute__((ext_vector_type(2)));
typedef _Float16 h8 __attribute__((ext_vector_type(8)));

// ---------------------------------------------------------------------------
// K1: cur[b,t,h] = sum_c x[b,t,c]*snn_w[h,c] + snn_b[h]     (fp32)
// ---------------------------------------------------------------------------
#define K1_TT 128
__global__ __launch_bounds__(256) void k_cur(const float* __restrict__ x,
                                             const float* __restrict__ w,
                                             const float* __restrict__ bias,
                                             float* __restrict__ cur) {
  __shared__ float xs[K1_TT * C_];  // 32 KB
  const int b = blockIdx.x;
  const int t0 = blockIdx.y * K1_TT;
  const int tid = threadIdx.x;

  const float4* xsrc = (const float4*)(x + ((size_t)b * T_ + t0) * C_);
  float4* xdst = (float4*)xs;
#pragma unroll
  for (int i = 0; i < (K1_TT * C_ / 4) / 256; i++)
    xdst[tid + i * 256] = xsrc[tid + i * 256];

  float wr[C_];
  const float4* wp = (const float4*)(w + (size_t)tid * C_);
#pragma unroll
  for (int q = 0; q < C_ / 4; q++) {
    float4 v = wp[q];
    wr[4 * q + 0] = v.x; wr[4 * q + 1] = v.y;
    wr[4 * q + 2] = v.z; wr[4 * q + 3] = v.w;
  }
  const float bb = bias[tid];
  __syncthreads();

  for (int t = 0; t < K1_TT; t++) {
    const float4* xrow = (const float4*)(xs + t * C_);
    float a0 = 0.f, a1 = 0.f;
#pragma unroll
    for (int q = 0; q < C_ / 4; q += 2) {
      float4 v0 = xrow[q];
      float4 v1 = xrow[q + 1];
      a0 += wr[4 * q + 0] * v0.x + wr[4 * q + 1] * v0.y +
            wr[4 * q + 2] * v0.z + wr[4 * q + 3] * v0.w;
      a1 += wr[4 * q + 4] * v1.x + wr[4 * q + 5] * v1.y +
            wr[4 * q + 6] * v1.z + wr[4 * q + 7] * v1.w;
    }
    cur[((size_t)b * T_ + t0 + t) * H_ + tid] = a0 + a1 + bb;
  }
}

// ---------------------------------------------------------------------------
// K2: LIF scan per (b,h). Spikes stored as u8 (exact).
// ---------------------------------------------------------------------------
__global__ __launch_bounds__(64) void k_lif(const float* __restrict__ cur,
                                            unsigned char* __restrict__ spk) {
  const int b = blockIdx.x >> 2;
  const int h = ((blockIdx.x & 3) << 6) + threadIdx.x;
  const float* cp = cur + (size_t)b * T_ * H_ + h;
  unsigned char* sp = spk + (size_t)b * T_ * H_ + h;
  float mem = 0.f;
#pragma unroll 8
  for (int t = 0; t < T_; t++) {
    float c = cp[(size_t)t * H_];
    float reset = (mem > 1.0f) ? 1.0f : 0.0f;  // from previous mem
    mem = 0.9f * mem + c - reset;              // THR = 1
    sp[(size_t)t * H_] = (mem > 1.0f) ? (unsigned char)1 : (unsigned char)0;
  }
}

// ---------------------------------------------------------------------------
// K3: gx[m,g] = sum_k hcomb[m,k]*wih[g,k] + bih[g]   -> stored fp16
//     hcomb = [x (k<64) | spk (k>=64)], M=131072, K=320, N=768
// fp32 LDS-tiled GEMM: BM=128 BN=64 BK=32, 256 threads, 4x8 per-thread tile.
// ---------------------------------------------------------------------------
#define BM 128
#define BN 64
#define BK 32
__global__ __launch_bounds__(256) void k_gx(const float* __restrict__ x,
                                            const unsigned char* __restrict__ spk,
                                            const float* __restrict__ wih,
                                            const float* __restrict__ bih,
                                            _Float16* __restrict__ gx) {
  __shared__ float As[BK][BM];  // 16 KB
  __shared__ float Bs[BK][BN];  // 8 KB
  const int nb = blockIdx.x;
  const int mb = blockIdx.y;
  const int m0 = mb * BM, n0 = nb * BN;
  const int tid = threadIdx.x;
  const int tm = (tid & 31) * 4;
  const int tn = (tid >> 5) * 8;

  float acc[4][8] = {};

  for (int k0 = 0; k0 < 320; k0 += BK) {
    if (k0 < 64) {
#pragma unroll
      for (int i = 0; i < 4; i++) {
        int idx = tid + i * 256;
        int r = idx >> 3;
        int c4 = (idx & 7) * 4;
        float4 v = *(const float4*)(x + (size_t)(m0 + r) * C_ + k0 + c4);
        As[c4 + 0][r] = v.x; As[c4 + 1][r] = v.y;
        As[c4 + 2][r] = v.z; As[c4 + 3][r] = v.w;
      }
    } else {
#pragma unroll
      for (int i = 0; i < 4; i++) {
        int idx = tid + i * 256;
        int r = idx >> 3;
        int c4 = (idx & 7) * 4;
        uchar4 u = *(const uchar4*)(spk + (size_t)(m0 + r) * H_ + (k0 - 64) + c4);
        As[c4 + 0][r] = (float)u.x; As[c4 + 1][r] = (float)u.y;
        As[c4 + 2][r] = (float)u.z; As[c4 + 3][r] = (float)u.w;
      }
    }
#pragma unroll
    for (int i = 0; i < 2; i++) {
      int idx = tid + i * 256;
      int r = idx >> 3;
      int c4 = (idx & 7) * 4;
      float4 v = *(const float4*)(wih + (size_t)(n0 + r) * 320 + k0 + c4);
      Bs[c4 + 0][r] = v.x; Bs[c4 + 1][r] = v.y;
      Bs[c4 + 2][r] = v.z; Bs[c4 + 3][r] = v.w;
    }
    __syncthreads();
#pragma unroll
    for (int k = 0; k < BK; k++) {
      float a[4], bv[8];
      *(float4*)&a[0] = *(const float4*)&As[k][tm];
      *(float4*)&bv[0] = *(const float4*)&Bs[k][tn];
      *(float4*)&bv[4] = *(const float4*)&Bs[k][tn + 4];
#pragma unroll
      for (int i = 0; i < 4; i++)
#pragma unroll
        for (int jj = 0; jj < 8; jj++) acc[i][jj] += a[i] * bv[jj];
    }
    __syncthreads();
  }
#pragma unroll
  for (int i = 0; i < 4; i++) {
    size_t m = (size_t)(m0 + tm + i);
    h8 o;
#pragma unroll
    for (int jj = 0; jj < 8; jj++)
      o[jj] = (_Float16)(acc[i][jj] + bih[n0 + tn + jj]);
    *(h8*)(gx + m * G3_ + n0 + tn) = o;
  }
}

// ---------------------------------------------------------------------------
// K4: GRU scan, one block per batch. 512 threads = (j in [0,256), kq in [0,2)).
// whh rows {j, 256+j, 512+j} x k-chunk [128*kq, 128*kq+128) as packed half2
// = 192 VGPRs/thread. __launch_bounds__(512,2) -> 256-VGPR cap so the weight
// slice stays in ARCH VGPRs (round-2 lesson: default bounds gave 128 VGPRs
// and pushed weights to AGPRs; v_dot2 can't read AGPRs -> accvgpr_read per
// use doubled the dot-phase VALU). h broadcast via ds_read_b128 (h8).
// ---------------------------------------------------------------------------
__global__ __launch_bounds__(512, 2) void k_gru(const _Float16* __restrict__ gx,
                                                const float* __restrict__ whh,
                                                const float* __restrict__ bhh,
                                                const float* __restrict__ head_w,
                                                const float* __restrict__ head_b,
                                                float* __restrict__ out) {
  const int b = blockIdx.x;
  const int tid = threadIdx.x;
  const int j = tid & (H_ - 1);
  const int kq = tid >> 8;       // 0 or 1
  const int k0 = kq * 128;

  alignas(16) __shared__ h2 hbuf16[2][H_ / 2];   // 1 KB — fp16 matvec input
  __shared__ float hbuf32[2][H_];                // 2 KB — fp32 state trajectory
  __shared__ float red[3][2][H_];                // 6 KB
  __shared__ float gxs[G3_];                     // 3 KB

  // weight slice -> packed half2 registers (192 VGPRs)
  h2 wr[64], wz[64], wn[64];
  {
    const float4* p0 = (const float4*)(whh + (size_t)j * H_ + k0);
    const float4* p1 = (const float4*)(whh + (size_t)(H_ + j) * H_ + k0);
    const float4* p2 = (const float4*)(whh + (size_t)(2 * H_ + j) * H_ + k0);
#pragma unroll
    for (int q = 0; q < 32; q++) {
      float4 a = p0[q];
      wr[2 * q].x = (_Float16)a.x; wr[2 * q].y = (_Float16)a.y;
      wr[2 * q + 1].x = (_Float16)a.z; wr[2 * q + 1].y = (_Float16)a.w;
      float4 c = p1[q];
      wz[2 * q].x = (_Float16)c.x; wz[2 * q].y = (_Float16)c.y;
      wz[2 * q + 1].x = (_Float16)c.z; wz[2 * q + 1].y = (_Float16)c.w;
      float4 d = p2[q];
      wn[2 * q].x = (_Float16)d.x; wn[2 * q].y = (_Float16)d.y;
      wn[2 * q + 1].x = (_Float16)d.z; wn[2 * q + 1].y = (_Float16)d.w;
    }
  }
  const float br_ = bhh[j], bz_ = bhh[H_ + j], bn_ = bhh[2 * H_ + j];
  if (tid < H_) hbuf32[0][tid] = 0.f;
  if (tid < H_ / 2) {
    h2 z0; z0.x = (_Float16)0.f; z0.y = (_Float16)0.f;
    hbuf16[0][tid] = z0;
  }
  __syncthreads();

  const _Float16* gxb = gx + (size_t)b * T_ * G3_;
  int cb = 0;
  for (int t = 0; t < T_; t++) {
    // phase 1: kq==1 waves prefetch gx_t into LDS (overlaps dot phase)
    if (kq == 1) {
      float g0 = (float)gxb[(size_t)t * G3_ + j];
      float g1 = (float)gxb[(size_t)t * G3_ + H_ + j];
      float g2 = (float)gxb[(size_t)t * G3_ + 2 * H_ + j];
      gxs[j] = g0; gxs[H_ + j] = g1; gxs[2 * H_ + j] = g2;
    }
    // phase 2: partial dots — h via wave-uniform ds_read_b128 broadcast
    const h8* hv8 = (const h8*)(hbuf16[cb] + kq * 64);
    float ar = 0.f, az = 0.f, an = 0.f;
#pragma unroll
    for (int qq = 0; qq < 16; qq++) {
      h8 hh = hv8[qq];
      const h2* hp = (const h2*)&hh;
#pragma unroll
      for (int i = 0; i < 4; i++) {
        ar = __builtin_amdgcn_fdot2(wr[4 * qq + i], hp[i], ar, false);
        az = __builtin_amdgcn_fdot2(wz[4 * qq + i], hp[i], az, false);
        an = __builtin_amdgcn_fdot2(wn[4 * qq + i], hp[i], an, false);
      }
    }
    red[0][kq][j] = ar; red[1][kq][j] = az; red[2][kq][j] = an;
    __syncthreads();
    // phase 3: reduce + gates + state update
    if (tid < H_) {
      float hr = red[0][0][tid] + red[0][1][tid] + br_;
      float hz = red[1][0][tid] + red[1][1][tid] + bz_;
      float hn = red[2][0][tid] + red[2][1][tid] + bn_;
      float xr = gxs[tid], xz = gxs[H_ + tid], xn = gxs[2 * H_ + tid];
      float r = 1.f / (1.f + __expf(-(xr + hr)));
      float z = 1.f / (1.f + __expf(-(xz + hz)));
      float pre = xn + r * hn;
      float e = __expf(2.f * pre);          // tanh(x) = 1 - 2/(e^{2x}+1)
      float n = 1.f - 2.f / (e + 1.f);
      float hnew = (1.f - z) * n + z * hbuf32[cb][tid];
      hbuf32[cb ^ 1][tid] = hnew;
      ((_Float16*)hbuf16[cb ^ 1])[tid] = (_Float16)hnew;
    }
    cb ^= 1;
    __syncthreads();
  }

  // fused head from fp32 h
  if (tid < HOR_) {
    const float4* hw = (const float4*)(head_w + (size_t)tid * H_);
    const float4* hv4 = (const float4*)hbuf32[cb];
    float acc = head_b[tid];
#pragma unroll
    for (int q = 0; q < H_ / 4; q++) {
      float4 w4 = hw[q];
      float4 v4 = hv4[q];
      acc += w4.x * v4.x + w4.y * v4.y + w4.z * v4.z + w4.w * v4.w;
    }
    out[(size_t)b * HOR_ + tid] = acc;
  }
}

// ---------------------------------------------------------------------------
extern "C" void kernel_launch(void* const* d_in, const int* in_sizes, int n_in,
                              void* d_out, int out_size, void* d_ws, size_t ws_size,
                              hipStream_t stream) {
  const float* x      = (const float*)d_in[0];
  const float* snn_w  = (const float*)d_in[1];
  const float* snn_b  = (const float*)d_in[2];
  const float* wih    = (const float*)d_in[3];
  const float* whh    = (const float*)d_in[4];
  const float* bih    = (const float*)d_in[5];
  const float* bhh    = (const float*)d_in[6];
  const float* head_w = (const float*)d_in[7];
  const float* head_b = (const float*)d_in[8];
  float* out = (float*)d_out;

  // ws layout (235 MB total):
  //   [0, 201326592)          gx fp16 [131072,768]
  //   [0, 134217728)          cur fp32 [131072,256] — alias, dead before k_gx
  //   [201326592, 234881024)  spk u8 [131072,256]
  char* ws = (char*)d_ws;
  _Float16* gx = (_Float16*)ws;
  float* cur = (float*)ws;
  unsigned char* spk = (unsigned char*)(ws + (size_t)201326592);

  k_cur<<<dim3(B_, T_ / K1_TT), 256, 0, stream>>>(x, snn_w, snn_b, cur);
  k_lif<<<dim3(256), 64, 0, stream>>>(cur, spk);
  k_gx<<<dim3(G3_ / BN, (B_ * T_) / BM), 256, 0, stream>>>(x, spk, wih, bih, gx);
  k_gru<<<dim3(B_), 512, 0, stream>>>(gx, whh, bhh, head_w, head_b, out);
}